// Round 12
// baseline (347.438 us; speedup 1.0000x reference)
//
#include <hip/hip_runtime.h>
#include <hip/hip_bf16.h>

#define B_N 128
#define T_N 2048
#define H_N 512

typedef __attribute__((ext_vector_type(8))) short bf16x8;   // 8 bf16 = 4 VGPRs
typedef __attribute__((ext_vector_type(4))) float f32x4;    // MFMA acc

union U4 { unsigned int i[4]; bf16x8 v; };

// RNE f32 -> bf16 (low 16 bits)
__device__ __forceinline__ unsigned int f2bf(float f) {
    unsigned int u = __float_as_uint(f);
    u += 0x7fffu + ((u >> 16) & 1u);
    return u >> 16;
}

// packed f32x2 -> bf16x2 (RNE), single VALU inst
__device__ __forceinline__ unsigned int cvtpk(float lo, float hi) {
    unsigned int r;
    asm("v_cvt_pk_bf16_f32 %0, %1, %2" : "=v"(r) : "v"(lo), "v"(hi));
    return r;
}

// x >= 0 always here (relu+relu)
__device__ __forceinline__ float tanh_fast(float x) {
    float e = __expf(2.f * x);
    float r = __builtin_amdgcn_rcpf(e + 1.f);
    return 1.f - 2.f * r;
}

#define FENCE asm volatile("" ::: "memory")
#define SBAR  do { FENCE; __builtin_amdgcn_s_barrier(); FENCE; } while (0)
#define VMCNT(n) asm volatile("s_waitcnt vmcnt(" #n ")" ::: "memory")
#define LGKM0    asm volatile("s_waitcnt lgkmcnt(0)" ::: "memory")

// ---------------------------------------------------------------------------
// K2: w2 (512x512 f32) -> bf16, pre-swizzled within each 1024B row:
// dst_byte(g,k) = g*1024 + ((k*2) ^ ((g&7)<<4)). XOR stays inside each 128B
// k-slice; slices staged LINEARLY into LDS; fragment read applies
// byte^((row&7)<<4), cancelling (even swizzle count along the path).
// ---------------------------------------------------------------------------
__global__ void k_w2prep(const float* __restrict__ w2, unsigned short* __restrict__ w2sw) {
    int c = blockIdx.x * 256 + threadIdx.x;      // 32768 chunks of 8 elems
    int g = c >> 6, kc = c & 63;
    const float4* s = reinterpret_cast<const float4*>(w2 + (size_t)g * H_N + kc * 8);
    float4 f0 = s[0], f1 = s[1];
    uint4 p;
    p.x = f2bf(f0.x) | (f2bf(f0.y) << 16);
    p.y = f2bf(f0.z) | (f2bf(f0.w) << 16);
    p.z = f2bf(f1.x) | (f2bf(f1.y) << 16);
    p.w = f2bf(f1.z) | (f2bf(f1.w) << 16);
    *reinterpret_cast<uint4*>(reinterpret_cast<char*>(w2sw) + (size_t)g * 1024 +
                              (((kc * 16) ^ ((g & 7) << 4)))) = p;
}

// ---------------------------------------------------------------------------
// K1: q_h[b][g] = relu(query[b]·w1[g])   (f32, tiny; w1 L2-resident)
// ---------------------------------------------------------------------------
__global__ void k_qh(const float* __restrict__ query, const float* __restrict__ w1,
                     float* __restrict__ qh) {
    int b = blockIdx.x;
    int g = threadIdx.x;                          // 512 threads
    __shared__ float q[H_N];
    q[g] = query[(size_t)b * H_N + g];
    __syncthreads();
    const float4* w = reinterpret_cast<const float4*>(w1 + (size_t)g * H_N);
    float acc = 0.f;
#pragma unroll 4
    for (int i = 0; i < H_N / 4; ++i) {
        float4 wv = w[i];
        acc += q[4*i] * wv.x + q[4*i+1] * wv.y + q[4*i+2] * wv.z + q[4*i+3] * wv.w;
    }
    qh[(size_t)b * H_N + g] = fmaxf(acc, 0.f);
}

// ---------------------------------------------------------------------------
// K3 (fused, PERSISTENT): 256 blocks x 1024 threads; block p owns the 16
// 64-row chunks of batch half (b = p>>1, c32 = (p&1)*16 + j).
// Per chunk: s_t = sum_g w_out[g]*tanh(qh+relu(key·w2)) -> w_t=exp(s_t);
//            psum += w_t;  partial[h] = sum_t w_t*key[t][h]  (PV from LDS).
// GEMM per chunk: BM=64 x BN=512(2 sweeps of 256) x K=512; BK=64, 16 steps.
// 16 waves 4wr x 4wc, wave tile 16t x 64g, acc[1][4]=16 regs.
//   A: 128KB key tile loaded CONTIGUOUSLY to regs at the PREVIOUS chunk's
//      end (HBM latency hidden under epilogue/softmax/PV), cvt_pk ->
//      full-K 64KB LDS tile (XOR swizzle). PV reads it from LDS.
//   B: 16 slices of 32KB, 2x32KB dbuf glds, staged 2 AHEAD, counted
//      VMCNT(2) — mid-loop only B is outstanding (A drains at boundaries).
// One kernel-wide prologue; chunk boundary = VMCNT(0) + WRITE_A + 2 stages.
// LDS 128KB -> 1 block/CU, 4 waves/SIMD. No spill (~100 VGPR < 128 cap).
// ---------------------------------------------------------------------------
__global__ __launch_bounds__(1024, 4) void k_scores(
    const float* __restrict__ key, const unsigned short* __restrict__ w2sw,
    const float* __restrict__ qh, const float* __restrict__ w_out,
    float* __restrict__ partial, float* __restrict__ psum)
{
    const int p    = blockIdx.x;        // 0..255
    const int b    = p >> 1;
    const int tid  = threadIdx.x;
    const int wid  = tid >> 6;
    const int lane = tid & 63;
    const int lrow = lane & 15;         // fragment row/col
    const int lq   = lane >> 4;         // 0..3 k-group
    const int wr   = wid >> 2;          // 0..3 t quarter (16 rows)
    const int wc   = wid & 3;           // 0..3 g quarter (64 g of 256)
    const int swz  = (lrow & 7) << 4;   // byte XOR for fragment reads

    // [0,64K): B slice dbuf 2x32KB; [64K,128K): A bf16 full-K tile 64x1024B
    __shared__ __align__(16) char smem[131072];
    char* Bb0 = smem;
    char* Ab  = smem + 65536;
    float* sscore = reinterpret_cast<float*>(smem);          // alias B buf0
    float* wlds   = reinterpret_cast<float*>(smem + 1024);   // alias B buf0

    const char* keyB = reinterpret_cast<const char*>(key);
    const char* w2sb = reinterpret_cast<const char*>(w2sw);

    // ---- per-block constants (loaded once; drained in prologue) ----
    float wo_r[2][4], qh_r[2][4];
#pragma unroll
    for (int sw = 0; sw < 2; ++sw)
#pragma unroll
        for (int n = 0; n < 4; ++n) {
            int g = sw * 256 + wc * 64 + n * 16 + lrow;
            wo_r[sw][n] = w_out[g];
            qh_r[sw][n] = qh[(size_t)b * H_N + g];
        }

    // A staging geometry: thread -> row (tid>>4), 4 swizzled 16B slots kc+16m
    const int arow = tid >> 4;          // 0..63
    const int kc   = tid & 15;          // 0..15
    int awoff[4];
#pragma unroll
    for (int m = 0; m < 4; ++m)
        awoff[m] = arow * 1024 + (((kc + 16 * m) ^ (arow & 7)) << 4);

    float4 rA[8];                        // next chunk's A slice (32 f32)

    // contiguous A load: 4 x 32B runs per thread (512B runs per wave)
#define LOAD_A(c32) do {                                                      \
        const char* base_ = keyB + ((size_t)b * T_N + (size_t)(c32) * 64 + arow) * 2048 \
                            + kc * 32;                                        \
        _Pragma("unroll")                                                     \
        for (int m_ = 0; m_ < 4; ++m_) {                                      \
            rA[2*m_]   = *reinterpret_cast<const float4*>(base_ + m_ * 512);  \
            rA[2*m_+1] = *reinterpret_cast<const float4*>(base_ + m_ * 512 + 16); \
        }                                                                     \
    } while (0)

#define WRITE_A() do {                                                        \
        _Pragma("unroll")                                                     \
        for (int m_ = 0; m_ < 4; ++m_) {                                      \
            U4 u_;                                                            \
            u_.i[0] = cvtpk(rA[2*m_].x,   rA[2*m_].y);                        \
            u_.i[1] = cvtpk(rA[2*m_].z,   rA[2*m_].w);                        \
            u_.i[2] = cvtpk(rA[2*m_+1].x, rA[2*m_+1].y);                      \
            u_.i[3] = cvtpk(rA[2*m_+1].z, rA[2*m_+1].w);                      \
            *reinterpret_cast<bf16x8*>(Ab + awoff[m_]) = u_.v;                \
        }                                                                     \
    } while (0)

    // B slice sl (0..15): sweep=sl>>3 (g rows +256), ksl=sl&7 -> buf sl&1
#define STAGE_B(sl) do {                                                      \
        char* dst_ = Bb0 + (((sl) & 1) << 15);                                \
        const char* src_ = w2sb + (((sl) >> 3) << 18) + (((sl) & 7) << 7);    \
        _Pragma("unroll")                                                     \
        for (int i_ = 0; i_ < 2; ++i_) {                                      \
            int c0_ = i_ * 1024 + wid * 64;                                   \
            int c_  = c0_ + lane;                                             \
            __builtin_amdgcn_global_load_lds(                                 \
                (const __attribute__((address_space(1))) void*)(src_ + (size_t)(c_ >> 3) * 1024 + (c_ & 7) * 16), \
                (__attribute__((address_space(3))) void*)(dst_ + c0_ * 16), 16, 0, 0); \
        }                                                                     \
    } while (0)

    f32x4 acc[4];
#pragma unroll
    for (int n = 0; n < 4; ++n) acc[n] = f32x4{0.f, 0.f, 0.f, 0.f};
    float pscore[4];

#define COMPUTE(s) do {                                                       \
        const char* Bc_ = Bb0 + (((s) & 1) << 15);                            \
        const int kb_ = ((s) & 7) << 7;                                       \
        _Pragma("unroll")                                                     \
        for (int ks_ = 0; ks_ < 2; ++ks_) {                                   \
            bf16x8 av_ = *reinterpret_cast<const bf16x8*>(                    \
                Ab + (wr * 16 + lrow) * 1024 + ((kb_ + ks_ * 64 + lq * 16) ^ swz)); \
            _Pragma("unroll")                                                 \
            for (int n_ = 0; n_ < 4; ++n_) {                                  \
                bf16x8 bv_ = *reinterpret_cast<const bf16x8*>(                \
                    Bc_ + (wc * 64 + n_ * 16 + lrow) * 128 + ((ks_ * 64 + lq * 16) ^ swz)); \
                acc[n_] = __builtin_amdgcn_mfma_f32_16x16x32_bf16(            \
                    av_, bv_, acc[n_], 0, 0, 0);                              \
            }                                                                 \
        }                                                                     \
    } while (0)

#define EPILOG(sw) do {                                                       \
        _Pragma("unroll")                                                     \
        for (int n_ = 0; n_ < 4; ++n_) {                                      \
            float wo_ = wo_r[sw][n_], qv_ = qh_r[sw][n_];                     \
            _Pragma("unroll")                                                 \
            for (int r_ = 0; r_ < 4; ++r_) {                                  \
                float x_ = qv_ + fmaxf(acc[n_][r_], 0.f);                     \
                pscore[r_] = fmaf(wo_, tanh_fast(x_), pscore[r_]);            \
            }                                                                 \
            acc[n_] = f32x4{0.f, 0.f, 0.f, 0.f};                              \
        }                                                                     \
    } while (0)

    // ---- kernel-wide prologue: A(chunk0), B(0), B(1) ----
    LOAD_A((p & 1) * 16);
    VMCNT(0);                 // A regs (+ const preloads) landed
    WRITE_A();
    STAGE_B(0); STAGE_B(1);
    VMCNT(2);                 // B(0) landed; B(1) in flight
    LGKM0;
    SBAR;

#pragma unroll 1
    for (int j = 0; j < 16; ++j) {
        const int c32 = (p & 1) * 16 + j;
        pscore[0] = pscore[1] = pscore[2] = pscore[3] = 0.f;

#pragma unroll 2
        for (int s = 0; s < 16; ++s) {
            COMPUTE(s);
            SBAR;                         // all waves done with buf s&1
            if (s < 14) STAGE_B(s + 2);   // refill just-freed buffer
            if (s == 7) EPILOG(0);        // sweep-0 epilogue hides B latency
            if (s < 14)      { VMCNT(2); SBAR; }   // B(s+1) landed
            else if (s == 14){ VMCNT(0); SBAR; }   // B(15) landed
            // s==15: fall out; chunk-end phase has its own barriers
        }

        if (j < 15) LOAD_A(c32 + 1);      // contiguous HBM burst, hidden below
        EPILOG(1);

        // ---- score reduce: 16 g-cols (lanes), then 4 wc waves via LDS ----
#pragma unroll
        for (int r = 0; r < 4; ++r) {
            float v = pscore[r];
            v += __shfl_xor(v, 1);
            v += __shfl_xor(v, 2);
            v += __shfl_xor(v, 4);
            v += __shfl_xor(v, 8);
            if (lrow == 0) sscore[wc * 64 + wr * 16 + lq * 4 + r] = v;
        }
        LGKM0; SBAR;

        // w_t = exp(s_t) (no max-sub: |s| <= Sum|w_out| ~ 18, exact shift)
        if (tid < 64)
            wlds[tid] = __expf(sscore[0 * 64 + tid] + sscore[1 * 64 + tid] +
                               sscore[2 * 64 + tid] + sscore[3 * 64 + tid]);
        LGKM0; SBAR;

        // ---- PV from the LDS A tile + psum ----
        float pv_a = 0.f;
        {
            const int h = tid & 511, th = tid >> 9;
#pragma unroll 8
            for (int t = th * 32; t < th * 32 + 32; ++t) {
                unsigned short uv = *reinterpret_cast<const unsigned short*>(
                    Ab + t * 1024 + ((2 * h) ^ ((t & 7) << 4)));
                pv_a = fmaf(wlds[t], __uint_as_float((unsigned)uv << 16), pv_a);
            }
        }
        if (wid == 0) {
            float v = wlds[lane];
            v += __shfl_xor(v, 1);
            v += __shfl_xor(v, 2);
            v += __shfl_xor(v, 4);
            v += __shfl_xor(v, 8);
            v += __shfl_xor(v, 16);
            v += __shfl_xor(v, 32);
            if (lane == 0) psum[b * 32 + c32] = v;
        }
        LGKM0; SBAR;              // PV reads of Ab/wlds done before overwrite

        if (j < 15) {
            VMCNT(0);             // next A regs landed (issued pre-epilogue)
            WRITE_A();
        }
        {
            const int h = tid & 511, th = tid >> 9;
            partial[((size_t)((b * 32 + c32) * 2 + th)) * 512 + h] = pv_a;
        }
        if (j < 15) {
            STAGE_B(0); STAGE_B(1);
            VMCNT(2);             // B(0') + stores done; B(1') in flight
            LGKM0;                // A ds_writes visible
            SBAR;
        }
    }

#undef LOAD_A
#undef WRITE_A
#undef STAGE_B
#undef COMPUTE
#undef EPILOG
}

// ---------------------------------------------------------------------------
// K4: out[b][h] = (sum_c,th partial[b][c][th][h]) / (sum_c psum[b][c])
// ---------------------------------------------------------------------------
__global__ void k_out(const float* __restrict__ partial, const float* __restrict__ psum,
                      float* __restrict__ out) {
    int idx = blockIdx.x * 256 + threadIdx.x;   // 65536 outputs
    int b = idx >> 9, h = idx & 511;
    float s = 0.f, d = 0.f;
#pragma unroll
    for (int c = 0; c < 32; ++c) {
        d += psum[b * 32 + c];
        s += partial[((size_t)((b * 32 + c) * 2 + 0)) * 512 + h] +
             partial[((size_t)((b * 32 + c) * 2 + 1)) * 512 + h];
    }
    out[idx] = s / d;
}

extern "C" void kernel_launch(void* const* d_in, const int* in_sizes, int n_in,
                              void* d_out, int out_size, void* d_ws, size_t ws_size,
                              hipStream_t stream) {
    const float* query = (const float*)d_in[0];
    const float* key   = (const float*)d_in[1];
    const float* w1    = (const float*)d_in[2];
    const float* w2    = (const float*)d_in[3];
    const float* w_out = (const float*)d_in[4];
    float* out = (float*)d_out;

    char* ws = (char*)d_ws;
    unsigned short* w2sw = (unsigned short*)(ws);            // 512 KB
    float* qh      = (float*)(ws + 524288);                  // 256 KB
    float* partial = (float*)(ws + 1048576);                 // 16 MB (8192*512*4)
    float* psum    = (float*)(ws + 17825792);                // 16 KB

    hipLaunchKernelGGL(k_w2prep, dim3(128), dim3(256),  0, stream, w2, w2sw);
    hipLaunchKernelGGL(k_qh,     dim3(128), dim3(512),  0, stream, query, w1, qh);
    hipLaunchKernelGGL(k_scores, dim3(256), dim3(1024), 0, stream,
                       key, w2sw, qh, w_out, partial, psum);
    hipLaunchKernelGGL(k_out,    dim3(256), dim3(256),  0, stream, partial, psum, out);
}

// Round 13
// 310.740 us; speedup vs baseline: 1.1181x; 1.1181x over previous
//
#include <hip/hip_runtime.h>
#include <hip/hip_bf16.h>

#define B_N 128
#define T_N 2048
#define H_N 512

typedef __attribute__((ext_vector_type(8))) short bf16x8;   // 8 bf16 = 4 VGPRs
typedef __attribute__((ext_vector_type(4))) float f32x4;    // MFMA acc

union U4 { unsigned int i[4]; bf16x8 v; };

// RNE f32 -> bf16 (low 16 bits)
__device__ __forceinline__ unsigned int f2bf(float f) {
    unsigned int u = __float_as_uint(f);
    u += 0x7fffu + ((u >> 16) & 1u);
    return u >> 16;
}

// packed f32x2 -> bf16x2 (RNE), single VALU inst
__device__ __forceinline__ unsigned int cvtpk(float lo, float hi) {
    unsigned int r;
    asm("v_cvt_pk_bf16_f32 %0, %1, %2" : "=v"(r) : "v"(lo), "v"(hi));
    return r;
}

// x >= 0 always here (relu+relu)
__device__ __forceinline__ float tanh_fast(float x) {
    float e = __expf(2.f * x);
    float r = __builtin_amdgcn_rcpf(e + 1.f);
    return 1.f - 2.f * r;
}

#define FENCE asm volatile("" ::: "memory")
#define SBAR  do { FENCE; __builtin_amdgcn_s_barrier(); FENCE; } while (0)
#define VMCNT(n) asm volatile("s_waitcnt vmcnt(" #n ")" ::: "memory")
#define LGKM0    asm volatile("s_waitcnt lgkmcnt(0)" ::: "memory")

// ---------------------------------------------------------------------------
// K2 (v2): w2 (512x512 f32) -> bf16, packed into 16 contiguous 32KB k-slices
// (kb = k>>5). Within slice kb: g-pair row (g>>1) is 128B; 16B slot index
//   slot(g,lq) = (((g&1)<<2) | lq) ^ ((g>>1)&7),   k = kb*32 + lq*8 + j.
// Slices are glds-copied LINEARLY into LDS; the fragment read recomputes the
// same slot -> each 8-lane group reads one full 128B row: conflict-free.
// ---------------------------------------------------------------------------
__global__ void k_w2prep(const float* __restrict__ w2, unsigned short* __restrict__ w2sw) {
    int c = blockIdx.x * 256 + threadIdx.x;      // 32768 chunks of 8 elems
    int g = c >> 6, sl8 = c & 63;
    int kb = sl8 >> 2, lq = sl8 & 3;
    const float4* s = reinterpret_cast<const float4*>(w2 + (size_t)g * H_N + kb * 32 + lq * 8);
    float4 f0 = s[0], f1 = s[1];
    uint4 p;
    p.x = f2bf(f0.x) | (f2bf(f0.y) << 16);
    p.y = f2bf(f0.z) | (f2bf(f0.w) << 16);
    p.z = f2bf(f1.x) | (f2bf(f1.y) << 16);
    p.w = f2bf(f1.z) | (f2bf(f1.w) << 16);
    int slot = (((g & 1) << 2) | lq) ^ ((g >> 1) & 7);
    *reinterpret_cast<uint4*>(reinterpret_cast<char*>(w2sw) +
                              kb * 32768 + (g >> 1) * 128 + (slot << 4)) = p;
}

// ---------------------------------------------------------------------------
// K1: q_h[b][g] = relu(query[b]·w1[g])   (f32, tiny; w1 L2-resident)
// ---------------------------------------------------------------------------
__global__ void k_qh(const float* __restrict__ query, const float* __restrict__ w1,
                     float* __restrict__ qh) {
    int b = blockIdx.x;
    int g = threadIdx.x;                          // 512 threads
    __shared__ float q[H_N];
    q[g] = query[(size_t)b * H_N + g];
    __syncthreads();
    const float4* w = reinterpret_cast<const float4*>(w1 + (size_t)g * H_N);
    float acc = 0.f;
#pragma unroll 4
    for (int i = 0; i < H_N / 4; ++i) {
        float4 wv = w[i];
        acc += q[4*i] * wv.x + q[4*i+1] * wv.y + q[4*i+2] * wv.z + q[4*i+3] * wv.w;
    }
    qh[(size_t)b * H_N + g] = fmaxf(acc, 0.f);
}

// ---------------------------------------------------------------------------
// K3 (fused): per block of 64 t-rows (grid 32 x 128):
//   s_t = sum_g w_out[g]*tanh(qh[b][g] + relu(key[b][t]·w2[g]))  -> w_t=exp(s_t)
//   psum[b][c] = sum_t w_t ;  partial[b][c][h] = sum_t w_t * key[t][h]
// r11 skeleton (2 blocks/CU, 8 waves 2wr x 4wc, BM=64, BN=512 single sweep,
// wave tile 32t x 128g, acc[2][8]=64) with the measured flaw fixed:
//   B (w2sw, L2): 16 slices of 32KB (BK=32), dbuf 2x32KB, staged TWO slots
//     ahead into the just-freed buffer; counted VMCNT(6/4), never 0 mid-loop.
//   A (key, HBM): r11's proven 0-conflict path: f32->regs on EVEN slots,
//     cvt_pk -> swizzled ds_write on ODD slots, dbuf 2x8KB (BK=64, slice
//     a = s>>1, k-half = s&1).
// LDS = 2x32K (B) + 2x8K (A) = 80KB exactly -> 2 blocks/CU, 4 waves/SIMD.
// Per-slot HBM share (~1600cy/pair) is the pole; LDS/MFMA/L2 fit under it.
// ---------------------------------------------------------------------------
__global__ __launch_bounds__(512, 4) void k_scores(
    const float* __restrict__ key, const unsigned short* __restrict__ w2sw,
    const float* __restrict__ qh, const float* __restrict__ w_out,
    float* __restrict__ partial, float* __restrict__ psum)
{
    const int b    = blockIdx.y;
    const int chnk = blockIdx.x;
    const int t0   = chnk * 64;
    const int tid  = threadIdx.x;
    const int wid  = tid >> 6;
    const int lane = tid & 63;
    const int lrow = lane & 15;        // fragment row/col
    const int lq   = lane >> 4;        // 0..3 k-group
    const int wr   = wid >> 2;         // 0..1 t half (32 rows)
    const int wc   = wid & 3;          // 0..3 g quarter (128 g of 512)
    const int swzA = (lrow & 7) << 4;  // byte XOR for A fragment reads
    // B fragment addressing (pair-packed rows): lane-constant pieces
    const int rowB  = wc * 64 + (lrow >> 1);                       // + n*8
    const int slotB = ((((lrow & 1) << 2) | lq) ^ ((lrow >> 1) & 7)) << 4;

    // [0,64K): B dbuf 2x32KB; [64K,80K): A dbuf 2x8KB
    __shared__ __align__(16) char smem[81920];
    char* Bbase = smem;
    char* Abase = smem + 65536;
    float* sscore = reinterpret_cast<float*>(smem);          // post-loop alias
    float* wlds   = reinterpret_cast<float*>(smem + 2048);   // post-loop alias

    const char* keybB = reinterpret_cast<const char*>(key + ((size_t)b * T_N + t0) * H_N);
    const char* w2sb  = reinterpret_cast<const char*>(w2sw);

    // A staging: thread -> (row = tid>>3, 8 f32 at col (tid&7)*8)
    const int arow = tid >> 3;
    const int acol = tid & 7;
    const char* asrc = keybB + (size_t)arow * 2048 + acol * 32;
    char* adst = Abase + arow * 128 + ((acol * 16) ^ ((arow & 7) << 4));

    float4 rA[2];            // A-slice f32 regs (one set; load even, write odd)

#define LOAD_A(a) do {                                           \
        const char* p_ = asrc + ((a) << 8);                      \
        rA[0] = *reinterpret_cast<const float4*>(p_);            \
        rA[1] = *reinterpret_cast<const float4*>(p_ + 16);       \
    } while (0)

#define WRITE_A(a) do {                                          \
        U4 u_;                                                   \
        u_.i[0] = cvtpk(rA[0].x, rA[0].y);                       \
        u_.i[1] = cvtpk(rA[0].z, rA[0].w);                       \
        u_.i[2] = cvtpk(rA[1].x, rA[1].y);                       \
        u_.i[3] = cvtpk(rA[1].z, rA[1].w);                       \
        *reinterpret_cast<bf16x8*>(adst + (((a) & 1) << 13)) = u_.v; \
    } while (0)

    // B slice kb (0..15): contiguous 32KB -> buf kb&1; linear glds copy
#define STAGE_B(kb) do {                                         \
        char* dst_ = Bbase + (((kb) & 1) << 15);                 \
        const char* src_ = w2sb + ((kb) << 15);                  \
        _Pragma("unroll")                                        \
        for (int i_ = 0; i_ < 4; ++i_) {                         \
            int c0_ = i_ * 512 + wid * 64;                       \
            int c_  = c0_ + lane;                                \
            __builtin_amdgcn_global_load_lds(                    \
                (const __attribute__((address_space(1))) void*)(src_ + c_ * 16), \
                (__attribute__((address_space(3))) void*)(dst_ + c0_ * 16), 16, 0, 0); \
        }                                                        \
    } while (0)

    f32x4 acc[2][8];
#pragma unroll
    for (int m = 0; m < 2; ++m)
#pragma unroll
        for (int n = 0; n < 8; ++n) acc[m][n] = f32x4{0.f, 0.f, 0.f, 0.f};

    // compute slot s (kb = s): A buf (s>>1)&1, k-half s&1; B buf s&1
#define COMPUTE(s) do {                                                       \
        const char* Acur_ = Abase + (((s >> 1) & 1) << 13);                   \
        const char* Bcur_ = Bbase + (((s) & 1) << 15);                        \
        const int kqa_ = ((s) & 1) * 64 + lq * 16;                            \
        bf16x8 av_[2];                                                        \
        _Pragma("unroll")                                                     \
        for (int m_ = 0; m_ < 2; ++m_)                                        \
            av_[m_] = *reinterpret_cast<const bf16x8*>(                       \
                Acur_ + (wr * 32 + m_ * 16 + lrow) * 128 + (kqa_ ^ swzA));    \
        _Pragma("unroll")                                                     \
        for (int nh_ = 0; nh_ < 2; ++nh_) {                                   \
            bf16x8 bv_[4];                                                    \
            _Pragma("unroll")                                                 \
            for (int j_ = 0; j_ < 4; ++j_)                                    \
                bv_[j_] = *reinterpret_cast<const bf16x8*>(                   \
                    Bcur_ + (rowB + (nh_ * 4 + j_) * 8) * 128 + slotB);       \
            _Pragma("unroll")                                                 \
            for (int m_ = 0; m_ < 2; ++m_)                                    \
                _Pragma("unroll")                                             \
                for (int j_ = 0; j_ < 4; ++j_)                                \
                    acc[m_][nh_ * 4 + j_] = __builtin_amdgcn_mfma_f32_16x16x32_bf16( \
                        av_[m_], bv_[j_], acc[m_][nh_ * 4 + j_], 0, 0, 0);    \
        }                                                                     \
    } while (0)

    // ---- prologue: A(0) regs+write, B(0)+B(1) staged ----
    LOAD_A(0);               // 2
    STAGE_B(0);              // 4
    STAGE_B(1);              // 4
    VMCNT(8);                // A(0) regs ready
    WRITE_A(0);
    VMCNT(4);                // B(0) landed; B(1) in flight
    LGKM0;
    SBAR;

    // ---- 16 slots; B staged 2 ahead; A loads even / writes odd ----
#define SLOT_EVEN(s) do {                                        \
        COMPUTE(s);                                              \
        SBAR;                                                    \
        STAGE_B((s) + 2);                                        \
        LOAD_A((s) / 2 + 1);                                     \
        VMCNT(6);            /* B(s+1) landed */                 \
        SBAR;                                                    \
    } while (0)

#define SLOT_ODD(s) do {                                         \
        COMPUTE(s);                                              \
        SBAR;                                                    \
        STAGE_B((s) + 2);                                        \
        VMCNT(4);            /* B(s+1) landed; A regs ready */   \
        WRITE_A(((s) + 1) / 2);                                  \
        LGKM0;                                                   \
        SBAR;                                                    \
    } while (0)

    SLOT_EVEN(0);  SLOT_ODD(1);
    SLOT_EVEN(2);  SLOT_ODD(3);
    SLOT_EVEN(4);  SLOT_ODD(5);
    SLOT_EVEN(6);  SLOT_ODD(7);
    SLOT_EVEN(8);  SLOT_ODD(9);
    SLOT_EVEN(10); SLOT_ODD(11);
    SLOT_EVEN(12); SLOT_ODD(13);

    // slot 14: nothing left to issue; drain B(15)
    COMPUTE(14);
    SBAR;
    VMCNT(0);
    SBAR;
    // slot 15
    COMPUTE(15);
    SBAR;                    // all LDS reads done before sscore aliases Bbuf

    // ---- epilogue: pscore = sum_n w_out*tanh(qh + relu(acc)) ----
    float pscore[2][4] = {};
#pragma unroll
    for (int n = 0; n < 8; ++n) {
        int g = wc * 128 + n * 16 + lrow;
        float wo = w_out[g];
        float qv = qh[(size_t)b * H_N + g];
#pragma unroll
        for (int m = 0; m < 2; ++m)
#pragma unroll
            for (int r = 0; r < 4; ++r) {
                float x = qv + fmaxf(acc[m][n][r], 0.f);
                pscore[m][r] = fmaf(wo, tanh_fast(x), pscore[m][r]);
            }
    }

    // ---- cross-lane (16 g-cols) then cross-wave (4 wc) score reduction ----
#pragma unroll
    for (int m = 0; m < 2; ++m)
#pragma unroll
        for (int r = 0; r < 4; ++r) {
            float v = pscore[m][r];
            v += __shfl_xor(v, 1);
            v += __shfl_xor(v, 2);
            v += __shfl_xor(v, 4);
            v += __shfl_xor(v, 8);
            if (lrow == 0)
                sscore[wc * 64 + wr * 32 + m * 16 + lq * 4 + r] = v;
        }
    __syncthreads();

    // ---- w_t = exp(s_t) (no max-sub: |s| <= Sum|w_out| ~ 18, exact shift) ----
    if (tid < 64)
        wlds[tid] = __expf(sscore[0 * 64 + tid] + sscore[1 * 64 + tid] +
                           sscore[2 * 64 + tid] + sscore[3 * 64 + tid]);
    __syncthreads();

    // ---- psum (wave 0) ----
    if (wid == 0) {
        float v = wlds[lane];
        v += __shfl_xor(v, 1);
        v += __shfl_xor(v, 2);
        v += __shfl_xor(v, 4);
        v += __shfl_xor(v, 8);
        v += __shfl_xor(v, 16);
        v += __shfl_xor(v, 32);
        if (lane == 0) psum[b * 32 + chnk] = v;
    }

    // ---- PV tail: partial[h] = sum_t w_t * key[t][h]; key tile L2-hot ----
    {
        const float* keyp = key + ((size_t)b * T_N + t0) * H_N + tid;
        float a0 = 0.f;
#pragma unroll 8
        for (int t = 0; t < 64; ++t)
            a0 = fmaf(wlds[t], keyp[(size_t)t * H_N], a0);
        partial[((size_t)(b * 32 + chnk)) * H_N + tid] = a0;
    }

#undef LOAD_A
#undef WRITE_A
#undef STAGE_B
#undef COMPUTE
#undef SLOT_EVEN
#undef SLOT_ODD
}

// ---------------------------------------------------------------------------
// K4: out[b][h] = (sum_c partial[b][c][h]) / (sum_c psum[b][c])
// ---------------------------------------------------------------------------
__global__ void k_out(const float* __restrict__ partial, const float* __restrict__ psum,
                      float* __restrict__ out) {
    int idx = blockIdx.x * 256 + threadIdx.x;   // 65536 outputs
    int b = idx >> 9, h = idx & 511;
    float s = 0.f, d = 0.f;
#pragma unroll
    for (int c = 0; c < 32; ++c) {
        s += partial[((size_t)(b * 32 + c)) * H_N + h];
        d += psum[b * 32 + c];
    }
    out[idx] = s / d;
}

extern "C" void kernel_launch(void* const* d_in, const int* in_sizes, int n_in,
                              void* d_out, int out_size, void* d_ws, size_t ws_size,
                              hipStream_t stream) {
    const float* query = (const float*)d_in[0];
    const float* key   = (const float*)d_in[1];
    const float* w1    = (const float*)d_in[2];
    const float* w2    = (const float*)d_in[3];
    const float* w_out = (const float*)d_in[4];
    float* out = (float*)d_out;

    char* ws = (char*)d_ws;
    unsigned short* w2sw = (unsigned short*)(ws);            // 512 KB
    float* qh      = (float*)(ws + 524288);                  // 256 KB
    float* partial = (float*)(ws + 1048576);                 // 8 MB (128*32*512*4)
    float* psum    = (float*)(ws + 9437184);                 // 16 KB

    hipLaunchKernelGGL(k_w2prep, dim3(128),     dim3(256), 0, stream, w2, w2sw);
    hipLaunchKernelGGL(k_qh,     dim3(128),     dim3(512), 0, stream, query, w1, qh);
    hipLaunchKernelGGL(k_scores, dim3(32, 128), dim3(512), 0, stream,
                       key, w2sw, qh, w_out, partial, psum);
    hipLaunchKernelGGL(k_out,    dim3(256),     dim3(256), 0, stream, partial, psum, out);
}

// Round 14
// 253.924 us; speedup vs baseline: 1.3683x; 1.2238x over previous
//
#include <hip/hip_runtime.h>
#include <hip/hip_bf16.h>

#define B_N 128
#define T_N 2048
#define H_N 512

typedef __attribute__((ext_vector_type(8))) short bf16x8;   // 8 bf16 = 4 VGPRs
typedef __attribute__((ext_vector_type(4))) float f32x4;    // MFMA acc

union U4 { unsigned int i[4]; bf16x8 v; };

// RNE f32 -> bf16 (low 16 bits)
__device__ __forceinline__ unsigned int f2bf(float f) {
    unsigned int u = __float_as_uint(f);
    u += 0x7fffu + ((u >> 16) & 1u);
    return u >> 16;
}

// packed f32x2 -> bf16x2 (RNE), single VALU inst
__device__ __forceinline__ unsigned int cvtpk(float lo, float hi) {
    unsigned int r;
    asm("v_cvt_pk_bf16_f32 %0, %1, %2" : "=v"(r) : "v"(lo), "v"(hi));
    return r;
}

// x >= 0 always here (relu+relu)
__device__ __forceinline__ float tanh_fast(float x) {
    float e = __expf(2.f * x);
    float r = __builtin_amdgcn_rcpf(e + 1.f);
    return 1.f - 2.f * r;
}

#define FENCE asm volatile("" ::: "memory")
#define SBAR  do { FENCE; __builtin_amdgcn_s_barrier(); FENCE; } while (0)
#define VMCNT(n) asm volatile("s_waitcnt vmcnt(" #n ")" ::: "memory")
#define LGKM0    asm volatile("s_waitcnt lgkmcnt(0)" ::: "memory")

// ---------------------------------------------------------------------------
// K2 (v3): pack w2 (512x512 f32) -> bf16 in per-wave MFMA FRAGMENT order:
// 16B chunk index t = [wc(3b) | ks(4b) | n(2b) | lane(6b)], byte off = t*16.
// Chunk content: lane's B-fragment for wave-column wc, k32-slice ks, n-frag n:
//   g = wc*64 + n*16 + (lane&15);  k = ks*32 + (lane>>4)*8 .. +8.
// k_scores waves then read B frags from L2 with perfectly coalesced dwordx4
// (64 lanes x 16B = 1KB contiguous per fragment) — NO LDS for B at all.
// ---------------------------------------------------------------------------
__global__ void k_w2prep(const float* __restrict__ w2, unsigned short* __restrict__ w2p) {
    int t = blockIdx.x * 256 + threadIdx.x;      // 0..32767
    int l  = t & 63;
    int n  = (t >> 6) & 3;
    int ks = (t >> 8) & 15;
    int wc = t >> 12;
    int g  = wc * 64 + n * 16 + (l & 15);
    int k0 = ks * 32 + (l >> 4) * 8;
    const float4* s = reinterpret_cast<const float4*>(w2 + (size_t)g * H_N + k0);
    float4 f0 = s[0], f1 = s[1];
    uint4 p;
    p.x = f2bf(f0.x) | (f2bf(f0.y) << 16);
    p.y = f2bf(f0.z) | (f2bf(f0.w) << 16);
    p.z = f2bf(f1.x) | (f2bf(f1.y) << 16);
    p.w = f2bf(f1.z) | (f2bf(f1.w) << 16);
    *reinterpret_cast<uint4*>(reinterpret_cast<char*>(w2p) + (size_t)t * 16) = p;
}

// ---------------------------------------------------------------------------
// K1: q_h[b][g] = relu(query[b]·w1[g])   (f32, tiny; w1 L2-resident)
// ---------------------------------------------------------------------------
__global__ void k_qh(const float* __restrict__ query, const float* __restrict__ w1,
                     float* __restrict__ qh) {
    int b = blockIdx.x;
    int g = threadIdx.x;                          // 512 threads
    __shared__ float q[H_N];
    q[g] = query[(size_t)b * H_N + g];
    __syncthreads();
    const float4* w = reinterpret_cast<const float4*>(w1 + (size_t)g * H_N);
    float acc = 0.f;
#pragma unroll 4
    for (int i = 0; i < H_N / 4; ++i) {
        float4 wv = w[i];
        acc += q[4*i] * wv.x + q[4*i+1] * wv.y + q[4*i+2] * wv.z + q[4*i+3] * wv.w;
    }
    qh[(size_t)b * H_N + g] = fmaxf(acc, 0.f);
}

// ---------------------------------------------------------------------------
// K3 (fused): per block of 64 t-rows (grid 32 x 128):
//   s_t = sum_g w_out[g]*tanh(qh[b][g] + relu(key[b][t]·w2[g]))  -> w_t=exp(s_t)
//   psum[b][c] = sum_t w_t ;  partial[b][c][h] = sum_t w_t * key_bf16[t][h]
// NEW STRUCTURE (r13 post-mortem: LDS traffic + barrier cadence = ceiling):
//   A (key): staged ONCE full-K into a 64KB LDS bf16 tile (f32->regs->cvtpk->
//     swizzled ds_write, proven 0-conflict). Read-only thereafter.
//   B (w2p): per-wave fragment-packed; each wave loads its B frags straight
//     from L2 into REGISTERS (4 coalesced dwordx4 per k32-slice), depth-2
//     prefetch, counted VMCNT(4). NO LDS for B.
//   => the 16-step K-loop has ZERO barriers. 8 waves (1wr x 8wc), wave tile
//   64t x 64g, acc[4][4]=64 regs, MFMA:ds_read = 16:4 per slice.
// LDS = 64K (A) + sscore/wlds ~2.3K -> 2 blocks/CU, 4 waves/SIMD.
// PV tail reads the A tile from LDS (bf16, as r8: absmax 4.9e-4).
// ---------------------------------------------------------------------------
__global__ __launch_bounds__(512, 4) void k_scores(
    const float* __restrict__ key, const unsigned short* __restrict__ w2p,
    const float* __restrict__ qh, const float* __restrict__ w_out,
    float* __restrict__ partial, float* __restrict__ psum)
{
    const int b    = blockIdx.y;
    const int chnk = blockIdx.x;
    const int t0   = chnk * 64;
    const int tid  = threadIdx.x;
    const int wid  = tid >> 6;      // wave's g-column wc = wid (1x8)
    const int lane = tid & 63;
    const int lrow = lane & 15;     // fragment row/col
    const int lq   = lane >> 4;     // 0..3 k-group
    const int xm   = lrow & 7;      // A-read slot XOR

    __shared__ __align__(16) char Ab[65536];     // 64 rows x 1024B bf16, swizzled slots
    __shared__ float sscore[8][64];
    __shared__ float wlds[64];

    // ---- A staging geometry: row = tid>>3, 16-f32 run col = (tid&7) ----
    const int arow = tid >> 3;
    const int acol = tid & 7;
    const int axm  = arow & 7;
    const float* asrc = key + ((size_t)b * T_N + t0 + arow) * H_N + acol * 16;

    // ---- B per-wave fragment base: wave wid, lane -> contiguous 16B ----
    const char* bptr = reinterpret_cast<const char*>(w2p) + wid * 65536 + lane * 16;

    float4 Ra[4], Rb[4];
    bf16x8 br0[4], br1[4];

#define ALOAD(p, R) do {                                                      \
        const float4* q_ = reinterpret_cast<const float4*>(asrc + (p) * 128); \
        R[0] = q_[0]; R[1] = q_[1]; R[2] = q_[2]; R[3] = q_[3];               \
    } while (0)

#define AWRITE(p, R) do {                                                     \
        U4 u0_, u1_;                                                          \
        u0_.i[0] = cvtpk(R[0].x, R[0].y); u0_.i[1] = cvtpk(R[0].z, R[0].w);   \
        u0_.i[2] = cvtpk(R[1].x, R[1].y); u0_.i[3] = cvtpk(R[1].z, R[1].w);   \
        u1_.i[0] = cvtpk(R[2].x, R[2].y); u1_.i[1] = cvtpk(R[2].z, R[2].w);   \
        u1_.i[2] = cvtpk(R[3].x, R[3].y); u1_.i[3] = cvtpk(R[3].z, R[3].w);   \
        *reinterpret_cast<bf16x8*>(Ab + arow * 1024 +                         \
            ((((p) * 16 + acol * 2)     ^ axm) << 4)) = u0_.v;                \
        *reinterpret_cast<bf16x8*>(Ab + arow * 1024 +                         \
            ((((p) * 16 + acol * 2 + 1) ^ axm) << 4)) = u1_.v;                \
    } while (0)

#define LOADB(sl, R) do {                                                     \
        R[0] = *reinterpret_cast<const bf16x8*>(bptr + (sl) * 4096);          \
        R[1] = *reinterpret_cast<const bf16x8*>(bptr + (sl) * 4096 + 1024);   \
        R[2] = *reinterpret_cast<const bf16x8*>(bptr + (sl) * 4096 + 2048);   \
        R[3] = *reinterpret_cast<const bf16x8*>(bptr + (sl) * 4096 + 3072);   \
    } while (0)

    f32x4 acc[4][4];

    // KSTEP: wait cur B-frags (counted), 4 A ds_reads + 16 MFMA, then
    // overwrite cur set with slice ks+2 (in-order issue: WAR-safe).
#define KSTEP(ks, CUR, CNT, ISSUE) do {                                       \
        VMCNT(CNT);                                                           \
        _Pragma("unroll")                                                     \
        for (int m_ = 0; m_ < 4; ++m_) {                                      \
            bf16x8 av_ = *reinterpret_cast<const bf16x8*>(                    \
                Ab + (m_ * 16 + lrow) * 1024 + ((((ks) * 4 + lq) ^ xm) << 4));\
            acc[m_][0] = __builtin_amdgcn_mfma_f32_16x16x32_bf16(av_, CUR[0], acc[m_][0], 0, 0, 0); \
            acc[m_][1] = __builtin_amdgcn_mfma_f32_16x16x32_bf16(av_, CUR[1], acc[m_][1], 0, 0, 0); \
            acc[m_][2] = __builtin_amdgcn_mfma_f32_16x16x32_bf16(av_, CUR[2], acc[m_][2], 0, 0, 0); \
            acc[m_][3] = __builtin_amdgcn_mfma_f32_16x16x32_bf16(av_, CUR[3], acc[m_][3], 0, 0, 0); \
        }                                                                     \
        if (ISSUE) LOADB((ks) + 2, CUR);                                      \
    } while (0)

    // ---- A staging (pipelined, 2 reg sets) + B slice 0/1 prefetch ----
    ALOAD(0, Ra); ALOAD(1, Rb);           // 8 out
    VMCNT(4);  AWRITE(0, Ra); ALOAD(2, Ra);   // 8 out
    VMCNT(4);  AWRITE(1, Rb); ALOAD(3, Rb);   // 8 out
    VMCNT(4);  AWRITE(2, Ra);
    LOADB(0, br0); LOADB(1, br1);         // 12 out
    VMCNT(8);  AWRITE(3, Rb);             // A all written; B0+B1 in flight
    LGKM0;                                 // this wave's ds_writes complete
    SBAR;                                  // raw barrier: B prefetch survives

#pragma unroll
    for (int m = 0; m < 4; ++m)
#pragma unroll
        for (int n = 0; n < 4; ++n) acc[m][n] = f32x4{0.f, 0.f, 0.f, 0.f};

    // ---- 16 k32-slices, ZERO barriers ----
    KSTEP(0,  br0, 4, 1); KSTEP(1,  br1, 4, 1);
    KSTEP(2,  br0, 4, 1); KSTEP(3,  br1, 4, 1);
    KSTEP(4,  br0, 4, 1); KSTEP(5,  br1, 4, 1);
    KSTEP(6,  br0, 4, 1); KSTEP(7,  br1, 4, 1);
    KSTEP(8,  br0, 4, 1); KSTEP(9,  br1, 4, 1);
    KSTEP(10, br0, 4, 1); KSTEP(11, br1, 4, 1);
    KSTEP(12, br0, 4, 1); KSTEP(13, br1, 4, 1);
    KSTEP(14, br0, 4, 0); KSTEP(15, br1, 0, 0);

    // ---- epilogue: pscore = sum_n w_out*tanh(qh + relu(acc)) ----
    float pscore[4][4] = {};        // [m][r]
#pragma unroll
    for (int n = 0; n < 4; ++n) {
        int g = wid * 64 + n * 16 + lrow;
        float wo = w_out[g];
        float qv = qh[(size_t)b * H_N + g];
#pragma unroll
        for (int m = 0; m < 4; ++m)
#pragma unroll
            for (int r = 0; r < 4; ++r) {
                float x = qv + fmaxf(acc[m][n][r], 0.f);
                pscore[m][r] = fmaf(wo, tanh_fast(x), pscore[m][r]);
            }
    }

    // ---- reduce over 16 frag cols (lanes), then over 8 waves via LDS ----
#pragma unroll
    for (int m = 0; m < 4; ++m)
#pragma unroll
        for (int r = 0; r < 4; ++r) {
            float v = pscore[m][r];
            v += __shfl_xor(v, 1);
            v += __shfl_xor(v, 2);
            v += __shfl_xor(v, 4);
            v += __shfl_xor(v, 8);
            if (lrow == 0) sscore[wid][m * 16 + lq * 4 + r] = v;
        }
    __syncthreads();

    // ---- w_t = exp(s_t) (no max-sub: |s| <= Sum|w_out| ~ 18, exact shift) ----
    if (tid < 64) {
        float s = 0.f;
#pragma unroll
        for (int w = 0; w < 8; ++w) s += sscore[w][tid];
        wlds[tid] = __expf(s);
    }
    __syncthreads();

    // ---- psum (wave 0) ----
    if (wid == 0) {
        float v = wlds[lane];
        v += __shfl_xor(v, 1);
        v += __shfl_xor(v, 2);
        v += __shfl_xor(v, 4);
        v += __shfl_xor(v, 8);
        v += __shfl_xor(v, 16);
        v += __shfl_xor(v, 32);
        if (lane == 0) psum[b * 32 + chnk] = v;
    }

    // ---- PV from the LDS A tile (bf16): partial[h] = sum_t w_t*key[t][h] ----
    {
        const int h = tid;          // 0..511
        float a0 = 0.f;
#pragma unroll 8
        for (int t = 0; t < 64; ++t) {
            int byte = t * 1024 + ((((h >> 3) ^ (t & 7)) << 4) | ((h & 7) << 1));
            unsigned short uv = *reinterpret_cast<const unsigned short*>(Ab + byte);
            a0 = fmaf(wlds[t], __uint_as_float((unsigned)uv << 16), a0);
        }
        partial[((size_t)(b * 32 + chnk)) * H_N + h] = a0;
    }

#undef ALOAD
#undef AWRITE
#undef LOADB
#undef KSTEP
}

// ---------------------------------------------------------------------------
// K4: out[b][h] = (sum_c partial[b][c][h]) / (sum_c psum[b][c])
// ---------------------------------------------------------------------------
__global__ void k_out(const float* __restrict__ partial, const float* __restrict__ psum,
                      float* __restrict__ out) {
    int idx = blockIdx.x * 256 + threadIdx.x;   // 65536 outputs
    int b = idx >> 9, h = idx & 511;
    float s = 0.f, d = 0.f;
#pragma unroll
    for (int c = 0; c < 32; ++c) {
        s += partial[((size_t)(b * 32 + c)) * H_N + h];
        d += psum[b * 32 + c];
    }
    out[idx] = s / d;
}

extern "C" void kernel_launch(void* const* d_in, const int* in_sizes, int n_in,
                              void* d_out, int out_size, void* d_ws, size_t ws_size,
                              hipStream_t stream) {
    const float* query = (const float*)d_in[0];
    const float* key   = (const float*)d_in[1];
    const float* w1    = (const float*)d_in[2];
    const float* w2    = (const float*)d_in[3];
    const float* w_out = (const float*)d_in[4];
    float* out = (float*)d_out;

    char* ws = (char*)d_ws;
    unsigned short* w2p = (unsigned short*)(ws);             // 512 KB
    float* qh      = (float*)(ws + 524288);                  // 256 KB
    float* partial = (float*)(ws + 1048576);                 // 8 MB (128*32*512*4)
    float* psum    = (float*)(ws + 9437184);                 // 16 KB

    hipLaunchKernelGGL(k_w2prep, dim3(128),     dim3(256), 0, stream, w2, w2p);
    hipLaunchKernelGGL(k_qh,     dim3(128),     dim3(512), 0, stream, query, w1, qh);
    hipLaunchKernelGGL(k_scores, dim3(32, 128), dim3(512), 0, stream,
                       key, w2p, qh, w_out, partial, psum);
    hipLaunchKernelGGL(k_out,    dim3(256),     dim3(256), 0, stream, partial, psum, out);
}

// Round 15
// 253.214 us; speedup vs baseline: 1.3721x; 1.0028x over previous
//
#include <hip/hip_runtime.h>
#include <hip/hip_bf16.h>

#define B_N 128
#define T_N 2048
#define H_N 512

typedef __attribute__((ext_vector_type(8))) short bf16x8;   // 8 bf16 = 4 VGPRs
typedef __attribute__((ext_vector_type(4))) float f32x4;    // MFMA acc

union U4 { unsigned int i[4]; bf16x8 v; };

// RNE f32 -> bf16 (low 16 bits)
__device__ __forceinline__ unsigned int f2bf(float f) {
    unsigned int u = __float_as_uint(f);
    u += 0x7fffu + ((u >> 16) & 1u);
    return u >> 16;
}

// packed f32x2 -> bf16x2 (RNE), single VALU inst
__device__ __forceinline__ unsigned int cvtpk(float lo, float hi) {
    unsigned int r;
    asm("v_cvt_pk_bf16_f32 %0, %1, %2" : "=v"(r) : "v"(lo), "v"(hi));
    return r;
}

// x >= 0 always here (relu+relu)
__device__ __forceinline__ float tanh_fast(float x) {
    float e = __expf(2.f * x);
    float r = __builtin_amdgcn_rcpf(e + 1.f);
    return 1.f - 2.f * r;
}

#define FENCE asm volatile("" ::: "memory")
#define SBAR  do { FENCE; __builtin_amdgcn_s_barrier(); FENCE; } while (0)
#define VMCNT(n) asm volatile("s_waitcnt vmcnt(" #n ")" ::: "memory")
#define LGKM0    asm volatile("s_waitcnt lgkmcnt(0)" ::: "memory")

// ---------------------------------------------------------------------------
// K2 (v3): pack w2 (512x512 f32) -> bf16 in per-wave MFMA FRAGMENT order:
// 16B chunk index t = [wc(3b) | ks(4b) | n(2b) | lane(6b)], byte off = t*16.
// Chunk content: lane's B-fragment for wave-column wc, k32-slice ks, n-frag n:
//   g = wc*64 + n*16 + (lane&15);  k = ks*32 + (lane>>4)*8 .. +8.
// k_scores waves then read B frags from L2 with perfectly coalesced dwordx4
// (64 lanes x 16B = 1KB contiguous per fragment) — NO LDS for B at all.
// ---------------------------------------------------------------------------
__global__ void k_w2prep(const float* __restrict__ w2, unsigned short* __restrict__ w2p) {
    int t = blockIdx.x * 256 + threadIdx.x;      // 0..32767
    int l  = t & 63;
    int n  = (t >> 6) & 3;
    int ks = (t >> 8) & 15;
    int wc = t >> 12;
    int g  = wc * 64 + n * 16 + (l & 15);
    int k0 = ks * 32 + (l >> 4) * 8;
    const float4* s = reinterpret_cast<const float4*>(w2 + (size_t)g * H_N + k0);
    float4 f0 = s[0], f1 = s[1];
    uint4 p;
    p.x = f2bf(f0.x) | (f2bf(f0.y) << 16);
    p.y = f2bf(f0.z) | (f2bf(f0.w) << 16);
    p.z = f2bf(f1.x) | (f2bf(f1.y) << 16);
    p.w = f2bf(f1.z) | (f2bf(f1.w) << 16);
    *reinterpret_cast<uint4*>(reinterpret_cast<char*>(w2p) + (size_t)t * 16) = p;
}

// ---------------------------------------------------------------------------
// K1: q_h[b][g] = relu(query[b]·w1[g])   (f32, tiny; w1 L2-resident)
// ---------------------------------------------------------------------------
__global__ void k_qh(const float* __restrict__ query, const float* __restrict__ w1,
                     float* __restrict__ qh) {
    int b = blockIdx.x;
    int g = threadIdx.x;                          // 512 threads
    __shared__ float q[H_N];
    q[g] = query[(size_t)b * H_N + g];
    __syncthreads();
    const float4* w = reinterpret_cast<const float4*>(w1 + (size_t)g * H_N);
    float acc = 0.f;
#pragma unroll 4
    for (int i = 0; i < H_N / 4; ++i) {
        float4 wv = w[i];
        acc += q[4*i] * wv.x + q[4*i+1] * wv.y + q[4*i+2] * wv.z + q[4*i+3] * wv.w;
    }
    qh[(size_t)b * H_N + g] = fmaxf(acc, 0.f);
}

// ---------------------------------------------------------------------------
// K3 (fused): per block of 64 t-rows (grid 32 x 128):
//   s_t = sum_g w_out[g]*tanh(qh[b][g] + relu(key[b][t]·w2[g]))  -> w_t=exp(s_t)
//   psum[b][c] = sum_t w_t ;  partial[b][c][h] = sum_t w_t * key_bf16[t][h]
// NEW STRUCTURE (r13 post-mortem: LDS traffic + barrier cadence = ceiling):
//   A (key): staged ONCE full-K into a 64KB LDS bf16 tile (f32->regs->cvtpk->
//     swizzled ds_write, proven 0-conflict). Read-only thereafter.
//   B (w2p): per-wave fragment-packed; each wave loads its B frags straight
//     from L2 into REGISTERS (4 coalesced dwordx4 per k32-slice), depth-2
//     prefetch, counted VMCNT(4). NO LDS for B.
//   => the 16-step K-loop has ZERO barriers. 8 waves (1wr x 8wc), wave tile
//   64t x 64g, acc[4][4]=64 regs, MFMA:ds_read = 16:4 per slice.
// LDS = 64K (A) + sscore/wlds ~2.3K -> 2 blocks/CU, 4 waves/SIMD.
// PV tail reads the A tile from LDS (bf16, as r8: absmax 4.9e-4).
// ---------------------------------------------------------------------------
__global__ __launch_bounds__(512, 4) void k_scores(
    const float* __restrict__ key, const unsigned short* __restrict__ w2p,
    const float* __restrict__ qh, const float* __restrict__ w_out,
    float* __restrict__ partial, float* __restrict__ psum)
{
    const int b    = blockIdx.y;
    const int chnk = blockIdx.x;
    const int t0   = chnk * 64;
    const int tid  = threadIdx.x;
    const int wid  = tid >> 6;      // wave's g-column wc = wid (1x8)
    const int lane = tid & 63;
    const int lrow = lane & 15;     // fragment row/col
    const int lq   = lane >> 4;     // 0..3 k-group
    const int xm   = lrow & 7;      // A-read slot XOR

    __shared__ __align__(16) char Ab[65536];     // 64 rows x 1024B bf16, swizzled slots
    __shared__ float sscore[8][64];
    __shared__ float wlds[64];

    // ---- A staging geometry: row = tid>>3, 16-f32 run col = (tid&7) ----
    const int arow = tid >> 3;
    const int acol = tid & 7;
    const int axm  = arow & 7;
    const float* asrc = key + ((size_t)b * T_N + t0 + arow) * H_N + acol * 16;

    // ---- B per-wave fragment base: wave wid, lane -> contiguous 16B ----
    const char* bptr = reinterpret_cast<const char*>(w2p) + wid * 65536 + lane * 16;

    float4 Ra[4], Rb[4];
    bf16x8 br0[4], br1[4];

#define ALOAD(p, R) do {                                                      \
        const float4* q_ = reinterpret_cast<const float4*>(asrc + (p) * 128); \
        R[0] = q_[0]; R[1] = q_[1]; R[2] = q_[2]; R[3] = q_[3];               \
    } while (0)

#define AWRITE(p, R) do {                                                     \
        U4 u0_, u1_;                                                          \
        u0_.i[0] = cvtpk(R[0].x, R[0].y); u0_.i[1] = cvtpk(R[0].z, R[0].w);   \
        u0_.i[2] = cvtpk(R[1].x, R[1].y); u0_.i[3] = cvtpk(R[1].z, R[1].w);   \
        u1_.i[0] = cvtpk(R[2].x, R[2].y); u1_.i[1] = cvtpk(R[2].z, R[2].w);   \
        u1_.i[2] = cvtpk(R[3].x, R[3].y); u1_.i[3] = cvtpk(R[3].z, R[3].w);   \
        *reinterpret_cast<bf16x8*>(Ab + arow * 1024 +                         \
            ((((p) * 16 + acol * 2)     ^ axm) << 4)) = u0_.v;                \
        *reinterpret_cast<bf16x8*>(Ab + arow * 1024 +                         \
            ((((p) * 16 + acol * 2 + 1) ^ axm) << 4)) = u1_.v;                \
    } while (0)

#define LOADB(sl, R) do {                                                     \
        R[0] = *reinterpret_cast<const bf16x8*>(bptr + (sl) * 4096);          \
        R[1] = *reinterpret_cast<const bf16x8*>(bptr + (sl) * 4096 + 1024);   \
        R[2] = *reinterpret_cast<const bf16x8*>(bptr + (sl) * 4096 + 2048);   \
        R[3] = *reinterpret_cast<const bf16x8*>(bptr + (sl) * 4096 + 3072);   \
    } while (0)

    f32x4 acc[4][4];

    // KSTEP: wait cur B-frags (counted), 4 A ds_reads + 16 MFMA, then
    // overwrite cur set with slice ks+2 (in-order issue: WAR-safe).
#define KSTEP(ks, CUR, CNT, ISSUE) do {                                       \
        VMCNT(CNT);                                                           \
        _Pragma("unroll")                                                     \
        for (int m_ = 0; m_ < 4; ++m_) {                                      \
            bf16x8 av_ = *reinterpret_cast<const bf16x8*>(                    \
                Ab + (m_ * 16 + lrow) * 1024 + ((((ks) * 4 + lq) ^ xm) << 4));\
            acc[m_][0] = __builtin_amdgcn_mfma_f32_16x16x32_bf16(av_, CUR[0], acc[m_][0], 0, 0, 0); \
            acc[m_][1] = __builtin_amdgcn_mfma_f32_16x16x32_bf16(av_, CUR[1], acc[m_][1], 0, 0, 0); \
            acc[m_][2] = __builtin_amdgcn_mfma_f32_16x16x32_bf16(av_, CUR[2], acc[m_][2], 0, 0, 0); \
            acc[m_][3] = __builtin_amdgcn_mfma_f32_16x16x32_bf16(av_, CUR[3], acc[m_][3], 0, 0, 0); \
        }                                                                     \
        if (ISSUE) LOADB((ks) + 2, CUR);                                      \
    } while (0)

    // ---- A staging (pipelined, 2 reg sets) + B slice 0/1 prefetch ----
    ALOAD(0, Ra); ALOAD(1, Rb);           // 8 out
    VMCNT(4);  AWRITE(0, Ra); ALOAD(2, Ra);   // 8 out
    VMCNT(4);  AWRITE(1, Rb); ALOAD(3, Rb);   // 8 out
    VMCNT(4);  AWRITE(2, Ra);
    LOADB(0, br0); LOADB(1, br1);         // 12 out
    VMCNT(8);  AWRITE(3, Rb);             // A all written; B0+B1 in flight
    LGKM0;                                 // this wave's ds_writes complete
    SBAR;                                  // raw barrier: B prefetch survives

#pragma unroll
    for (int m = 0; m < 4; ++m)
#pragma unroll
        for (int n = 0; n < 4; ++n) acc[m][n] = f32x4{0.f, 0.f, 0.f, 0.f};

    // ---- 16 k32-slices, ZERO barriers ----
    KSTEP(0,  br0, 4, 1); KSTEP(1,  br1, 4, 1);
    KSTEP(2,  br0, 4, 1); KSTEP(3,  br1, 4, 1);
    KSTEP(4,  br0, 4, 1); KSTEP(5,  br1, 4, 1);
    KSTEP(6,  br0, 4, 1); KSTEP(7,  br1, 4, 1);
    KSTEP(8,  br0, 4, 1); KSTEP(9,  br1, 4, 1);
    KSTEP(10, br0, 4, 1); KSTEP(11, br1, 4, 1);
    KSTEP(12, br0, 4, 1); KSTEP(13, br1, 4, 1);
    KSTEP(14, br0, 4, 0); KSTEP(15, br1, 0, 0);

    // ---- epilogue: pscore = sum_n w_out*tanh(qh + relu(acc)) ----
    float pscore[4][4] = {};        // [m][r]
#pragma unroll
    for (int n = 0; n < 4; ++n) {
        int g = wid * 64 + n * 16 + lrow;
        float wo = w_out[g];
        float qv = qh[(size_t)b * H_N + g];
#pragma unroll
        for (int m = 0; m < 4; ++m)
#pragma unroll
            for (int r = 0; r < 4; ++r) {
                float x = qv + fmaxf(acc[m][n][r], 0.f);
                pscore[m][r] = fmaf(wo, tanh_fast(x), pscore[m][r]);
            }
    }

    // ---- reduce over 16 frag cols (lanes), then over 8 waves via LDS ----
#pragma unroll
    for (int m = 0; m < 4; ++m)
#pragma unroll
        for (int r = 0; r < 4; ++r) {
            float v = pscore[m][r];
            v += __shfl_xor(v, 1);
            v += __shfl_xor(v, 2);
            v += __shfl_xor(v, 4);
            v += __shfl_xor(v, 8);
            if (lrow == 0) sscore[wid][m * 16 + lq * 4 + r] = v;
        }
    __syncthreads();

    // ---- w_t = exp(s_t) (no max-sub: |s| <= Sum|w_out| ~ 18, exact shift) ----
    if (tid < 64) {
        float s = 0.f;
#pragma unroll
        for (int w = 0; w < 8; ++w) s += sscore[w][tid];
        wlds[tid] = __expf(s);
    }
    __syncthreads();

    // ---- psum (wave 0) ----
    if (wid == 0) {
        float v = wlds[lane];
        v += __shfl_xor(v, 1);
        v += __shfl_xor(v, 2);
        v += __shfl_xor(v, 4);
        v += __shfl_xor(v, 8);
        v += __shfl_xor(v, 16);
        v += __shfl_xor(v, 32);
        if (lane == 0) psum[b * 32 + chnk] = v;
    }

    // ---- PV from the LDS A tile (bf16): partial[h] = sum_t w_t*key[t][h] ----
    {
        const int h = tid;          // 0..511
        float a0 = 0.f;
#pragma unroll 8
        for (int t = 0; t < 64; ++t) {
            int byte = t * 1024 + ((((h >> 3) ^ (t & 7)) << 4) | ((h & 7) << 1));
            unsigned short uv = *reinterpret_cast<const unsigned short*>(Ab + byte);
            a0 = fmaf(wlds[t], __uint_as_float((unsigned)uv << 16), a0);
        }
        partial[((size_t)(b * 32 + chnk)) * H_N + h] = a0;
    }

#undef ALOAD
#undef AWRITE
#undef LOADB
#undef KSTEP
}

// ---------------------------------------------------------------------------
// K4: out[b][h] = (sum_c partial[b][c][h]) / (sum_c psum[b][c])
// ---------------------------------------------------------------------------
__global__ void k_out(const float* __restrict__ partial, const float* __restrict__ psum,
                      float* __restrict__ out) {
    int idx = blockIdx.x * 256 + threadIdx.x;   // 65536 outputs
    int b = idx >> 9, h = idx & 511;
    float s = 0.f, d = 0.f;
#pragma unroll
    for (int c = 0; c < 32; ++c) {
        s += partial[((size_t)(b * 32 + c)) * H_N + h];
        d += psum[b * 32 + c];
    }
    out[idx] = s / d;
}

extern "C" void kernel_launch(void* const* d_in, const int* in_sizes, int n_in,
                              void* d_out, int out_size, void* d_ws, size_t ws_size,
                              hipStream_t stream) {
    const float* query = (const float*)d_in[0];
    const float* key   = (const float*)d_in[1];
    const float* w1    = (const float*)d_in[2];
    const float* w2    = (const float*)d_in[3];
    const float* w_out = (const float*)d_in[4];
    float* out = (float*)d_out;

    char* ws = (char*)d_ws;
    unsigned short* w2p = (unsigned short*)(ws);             // 512 KB
    float* qh      = (float*)(ws + 524288);                  // 256 KB
    float* partial = (float*)(ws + 1048576);                 // 8 MB (128*32*512*4)
    float* psum    = (float*)(ws + 9437184);                 // 16 KB

    hipLaunchKernelGGL(k_w2prep, dim3(128),     dim3(256), 0, stream, w2, w2p);
    hipLaunchKernelGGL(k_qh,     dim3(128),     dim3(512), 0, stream, query, w1, qh);
    hipLaunchKernelGGL(k_scores, dim3(32, 128), dim3(512), 0, stream,
                       key, w2p, qh, w_out, partial, psum);
    hipLaunchKernelGGL(k_out,    dim3(256),     dim3(256), 0, stream, partial, psum, out);
}

// Round 16
// 240.073 us; speedup vs baseline: 1.4472x; 1.0547x over previous
//
#include <hip/hip_runtime.h>
#include <hip/hip_bf16.h>

#define B_N 128
#define T_N 2048
#define H_N 512

typedef __attribute__((ext_vector_type(8))) short bf16x8;   // 8 bf16 = 4 VGPRs
typedef __attribute__((ext_vector_type(4))) float f32x4;    // MFMA acc

union U4 { unsigned int i[4]; bf16x8 v; };

// RNE f32 -> bf16 (low 16 bits)
__device__ __forceinline__ unsigned int f2bf(float f) {
    unsigned int u = __float_as_uint(f);
    u += 0x7fffu + ((u >> 16) & 1u);
    return u >> 16;
}

// packed f32x2 -> bf16x2 (RNE), single VALU inst
__device__ __forceinline__ unsigned int cvtpk(float lo, float hi) {
    unsigned int r;
    asm("v_cvt_pk_bf16_f32 %0, %1, %2" : "=v"(r) : "v"(lo), "v"(hi));
    return r;
}

// x >= 0 always here (relu+relu)
__device__ __forceinline__ float tanh_fast(float x) {
    float e = __expf(2.f * x);
    float r = __builtin_amdgcn_rcpf(e + 1.f);
    return 1.f - 2.f * r;
}

#define FENCE asm volatile("" ::: "memory")
#define SBAR  do { FENCE; __builtin_amdgcn_s_barrier(); FENCE; } while (0)
#define VMCNT(n) asm volatile("s_waitcnt vmcnt(" #n ")" ::: "memory")
#define LGKM0    asm volatile("s_waitcnt lgkmcnt(0)" ::: "memory")
#define SCHED0   __builtin_amdgcn_sched_barrier(0)

// ---------------------------------------------------------------------------
// K2 (v3): pack w2 (512x512 f32) -> bf16 in per-wave MFMA FRAGMENT order:
// 16B chunk index t = [wc(3b) | ks(4b) | n(2b) | lane(6b)], byte off = t*16.
// Chunk content: lane's B-fragment for wave-column wc, k32-slice ks, n-frag n:
//   g = wc*64 + n*16 + (lane&15);  k = ks*32 + (lane>>4)*8 .. +8.
// k_scores waves read B frags from L2 with perfectly coalesced dwordx4
// (64 lanes x 16B = 1KB contiguous per fragment) — NO LDS for B at all.
// ---------------------------------------------------------------------------
__global__ void k_w2prep(const float* __restrict__ w2, unsigned short* __restrict__ w2p) {
    int t = blockIdx.x * 256 + threadIdx.x;      // 0..32767
    int l  = t & 63;
    int n  = (t >> 6) & 3;
    int ks = (t >> 8) & 15;
    int wc = t >> 12;
    int g  = wc * 64 + n * 16 + (l & 15);
    int k0 = ks * 32 + (l >> 4) * 8;
    const float4* s = reinterpret_cast<const float4*>(w2 + (size_t)g * H_N + k0);
    float4 f0 = s[0], f1 = s[1];
    uint4 p;
    p.x = f2bf(f0.x) | (f2bf(f0.y) << 16);
    p.y = f2bf(f0.z) | (f2bf(f0.w) << 16);
    p.z = f2bf(f1.x) | (f2bf(f1.y) << 16);
    p.w = f2bf(f1.z) | (f2bf(f1.w) << 16);
    *reinterpret_cast<uint4*>(reinterpret_cast<char*>(w2p) + (size_t)t * 16) = p;
}

// ---------------------------------------------------------------------------
// K1: q_h[b][g] = relu(query[b]·w1[g])   (f32, tiny; w1 L2-resident)
// ---------------------------------------------------------------------------
__global__ void k_qh(const float* __restrict__ query, const float* __restrict__ w1,
                     float* __restrict__ qh) {
    int b = blockIdx.x;
    int g = threadIdx.x;                          // 512 threads
    __shared__ float q[H_N];
    q[g] = query[(size_t)b * H_N + g];
    __syncthreads();
    const float4* w = reinterpret_cast<const float4*>(w1 + (size_t)g * H_N);
    float acc = 0.f;
#pragma unroll 4
    for (int i = 0; i < H_N / 4; ++i) {
        float4 wv = w[i];
        acc += q[4*i] * wv.x + q[4*i+1] * wv.y + q[4*i+2] * wv.z + q[4*i+3] * wv.w;
    }
    qh[(size_t)b * H_N + g] = fmaxf(acc, 0.f);
}

// ---------------------------------------------------------------------------
// K3 (fused): per block of 64 t-rows (grid 32 x 128):
//   s_t = sum_g w_out[g]*tanh(qh[b][g] + relu(key[b][t]·w2[g]))  -> w_t=exp(s_t)
//   psum[b][c] = sum_t w_t ;  partial[b][c][h] = sum_t w_t * key_bf16[t][h]
// r14 structure (confirmed): A staged once full-K into 64KB LDS bf16 tile;
// B per-wave fragment-packed, loaded L2->regs depth-2; ZERO-barrier K-loop.
// r16 micro-fixes from the latency model:
//   - KSTEP: A ds_reads hoisted BEFORE the B VMCNT (latencies overlap);
//     sched_barrier(0) after the wait (rule #18 vmcnt analog);
//     s_setprio(1) around the 16-MFMA cluster (T5: independent waves).
//   - PV tail: 8 x ds_read_b128/wave (was 64 x u16) — swizzle makes
//     h-block == lane for every t; cross-wave reduce via LDS alias.
// LDS ~67.8KB -> 2 blocks/CU, 4 waves/SIMD. VGPR <= 128 (B depth stays 2).
// ---------------------------------------------------------------------------
__global__ __launch_bounds__(512, 4) void k_scores(
    const float* __restrict__ key, const unsigned short* __restrict__ w2p,
    const float* __restrict__ qh, const float* __restrict__ w_out,
    float* __restrict__ partial, float* __restrict__ psum)
{
    const int b    = blockIdx.y;
    const int chnk = blockIdx.x;
    const int t0   = chnk * 64;
    const int tid  = threadIdx.x;
    const int wid  = tid >> 6;      // wave's g-column wc = wid (1x8)
    const int lane = tid & 63;
    const int lrow = lane & 15;     // fragment row/col
    const int lq   = lane >> 4;     // 0..3 k-group
    const int xm   = lrow & 7;      // A-read slot XOR

    __shared__ __align__(16) char Ab[65536];     // 64 rows x 1024B bf16, swizzled slots
    __shared__ float sscore[8][64];
    __shared__ float wlds[64];

    // ---- A staging geometry: row = tid>>3, 16-f32 run col = (tid&7) ----
    const int arow = tid >> 3;
    const int acol = tid & 7;
    const int axm  = arow & 7;
    const float* asrc = key + ((size_t)b * T_N + t0 + arow) * H_N + acol * 16;

    // ---- B per-wave fragment base: wave wid, lane -> contiguous 16B ----
    const char* bptr = reinterpret_cast<const char*>(w2p) + wid * 65536 + lane * 16;

    float4 Ra[4], Rb[4];
    bf16x8 br0[4], br1[4];

#define ALOAD(p, R) do {                                                      \
        const float4* q_ = reinterpret_cast<const float4*>(asrc + (p) * 128); \
        R[0] = q_[0]; R[1] = q_[1]; R[2] = q_[2]; R[3] = q_[3];               \
    } while (0)

#define AWRITE(p, R) do {                                                     \
        U4 u0_, u1_;                                                          \
        u0_.i[0] = cvtpk(R[0].x, R[0].y); u0_.i[1] = cvtpk(R[0].z, R[0].w);   \
        u0_.i[2] = cvtpk(R[1].x, R[1].y); u0_.i[3] = cvtpk(R[1].z, R[1].w);   \
        u1_.i[0] = cvtpk(R[2].x, R[2].y); u1_.i[1] = cvtpk(R[2].z, R[2].w);   \
        u1_.i[2] = cvtpk(R[3].x, R[3].y); u1_.i[3] = cvtpk(R[3].z, R[3].w);   \
        *reinterpret_cast<bf16x8*>(Ab + arow * 1024 +                         \
            ((((p) * 16 + acol * 2)     ^ axm) << 4)) = u0_.v;                \
        *reinterpret_cast<bf16x8*>(Ab + arow * 1024 +                         \
            ((((p) * 16 + acol * 2 + 1) ^ axm) << 4)) = u1_.v;                \
    } while (0)

#define LOADB(sl, R) do {                                                     \
        R[0] = *reinterpret_cast<const bf16x8*>(bptr + (sl) * 4096);          \
        R[1] = *reinterpret_cast<const bf16x8*>(bptr + (sl) * 4096 + 1024);   \
        R[2] = *reinterpret_cast<const bf16x8*>(bptr + (sl) * 4096 + 2048);   \
        R[3] = *reinterpret_cast<const bf16x8*>(bptr + (sl) * 4096 + 3072);   \
    } while (0)

    f32x4 acc[4][4];

    // KSTEP: A ds_reads FIRST (latency overlaps the B wait), counted VMCNT,
    // sched fence (rule #18), prioritized MFMA cluster, then refill CUR.
#define KSTEP(ks, CUR, CNT, ISSUE) do {                                       \
        bf16x8 av_[4];                                                        \
        _Pragma("unroll")                                                     \
        for (int m_ = 0; m_ < 4; ++m_)                                        \
            av_[m_] = *reinterpret_cast<const bf16x8*>(                       \
                Ab + (m_ * 16 + lrow) * 1024 + ((((ks) * 4 + lq) ^ xm) << 4));\
        VMCNT(CNT);                                                           \
        SCHED0;                                                               \
        __builtin_amdgcn_s_setprio(1);                                        \
        _Pragma("unroll")                                                     \
        for (int m_ = 0; m_ < 4; ++m_) {                                      \
            acc[m_][0] = __builtin_amdgcn_mfma_f32_16x16x32_bf16(av_[m_], CUR[0], acc[m_][0], 0, 0, 0); \
            acc[m_][1] = __builtin_amdgcn_mfma_f32_16x16x32_bf16(av_[m_], CUR[1], acc[m_][1], 0, 0, 0); \
            acc[m_][2] = __builtin_amdgcn_mfma_f32_16x16x32_bf16(av_[m_], CUR[2], acc[m_][2], 0, 0, 0); \
            acc[m_][3] = __builtin_amdgcn_mfma_f32_16x16x32_bf16(av_[m_], CUR[3], acc[m_][3], 0, 0, 0); \
        }                                                                     \
        __builtin_amdgcn_s_setprio(0);                                        \
        if (ISSUE) LOADB((ks) + 2, CUR);                                      \
    } while (0)

    // ---- A staging (pipelined, 2 reg sets) + B slice 0/1 prefetch ----
    ALOAD(0, Ra); ALOAD(1, Rb);               // 8 out
    VMCNT(4);  AWRITE(0, Ra); ALOAD(2, Ra);   // 8 out
    VMCNT(4);  AWRITE(1, Rb); ALOAD(3, Rb);   // 8 out
    VMCNT(4);  AWRITE(2, Ra);
    LOADB(0, br0); LOADB(1, br1);             // 12 out
    VMCNT(8);  AWRITE(3, Rb);                 // A all written; B0+B1 in flight
    LGKM0;                                    // this wave's ds_writes complete
    SBAR;                                     // raw barrier: B prefetch survives

#pragma unroll
    for (int m = 0; m < 4; ++m)
#pragma unroll
        for (int n = 0; n < 4; ++n) acc[m][n] = f32x4{0.f, 0.f, 0.f, 0.f};

    // ---- 16 k32-slices, ZERO barriers ----
    KSTEP(0,  br0, 4, 1); KSTEP(1,  br1, 4, 1);
    KSTEP(2,  br0, 4, 1); KSTEP(3,  br1, 4, 1);
    KSTEP(4,  br0, 4, 1); KSTEP(5,  br1, 4, 1);
    KSTEP(6,  br0, 4, 1); KSTEP(7,  br1, 4, 1);
    KSTEP(8,  br0, 4, 1); KSTEP(9,  br1, 4, 1);
    KSTEP(10, br0, 4, 1); KSTEP(11, br1, 4, 1);
    KSTEP(12, br0, 4, 1); KSTEP(13, br1, 4, 1);
    KSTEP(14, br0, 4, 0); KSTEP(15, br1, 0, 0);

    // ---- epilogue: pscore = sum_n w_out*tanh(qh + relu(acc)) ----
    float pscore[4][4] = {};        // [m][r]
#pragma unroll
    for (int n = 0; n < 4; ++n) {
        int g = wid * 64 + n * 16 + lrow;
        float wo = w_out[g];
        float qv = qh[(size_t)b * H_N + g];
#pragma unroll
        for (int m = 0; m < 4; ++m)
#pragma unroll
            for (int r = 0; r < 4; ++r) {
                float x = qv + fmaxf(acc[m][n][r], 0.f);
                pscore[m][r] = fmaf(wo, tanh_fast(x), pscore[m][r]);
            }
    }

    // ---- reduce over 16 frag cols (lanes), then over 8 waves via LDS ----
#pragma unroll
    for (int m = 0; m < 4; ++m)
#pragma unroll
        for (int r = 0; r < 4; ++r) {
            float v = pscore[m][r];
            v += __shfl_xor(v, 1);
            v += __shfl_xor(v, 2);
            v += __shfl_xor(v, 4);
            v += __shfl_xor(v, 8);
            if (lrow == 0) sscore[wid][m * 16 + lq * 4 + r] = v;
        }
    __syncthreads();

    // ---- w_t = exp(s_t) (no max-sub: |s| <= Sum|w_out| ~ 18, exact shift) ----
    if (tid < 64) {
        float s = 0.f;
#pragma unroll
        for (int w = 0; w < 8; ++w) s += sscore[w][tid];
        wlds[tid] = __expf(s);
    }
    __syncthreads();

    // ---- psum (wave 0, overlaps PV) ----
    if (wid == 0) {
        float v = wlds[lane];
        v += __shfl_xor(v, 1);
        v += __shfl_xor(v, 2);
        v += __shfl_xor(v, 4);
        v += __shfl_xor(v, 8);
        v += __shfl_xor(v, 16);
        v += __shfl_xor(v, 32);
        if (lane == 0) psum[b * 32 + chnk] = v;
    }

    // ---- PV from LDS A tile, b128 reads: wave wid covers t in [8wid,+8);
    // swizzle identity: slot = lane^(t&7) holds h-block == lane for all t ----
    float pv[8] = {};
#pragma unroll
    for (int i = 0; i < 8; ++i) {
        int t = wid * 8 + i;
        bf16x8 kv = *reinterpret_cast<const bf16x8*>(
            Ab + t * 1024 + ((lane ^ i) << 4));
        float wt = wlds[t];
#pragma unroll
        for (int e = 0; e < 8; ++e)
            pv[e] = fmaf(wt, __uint_as_float((unsigned)(unsigned short)kv[e] << 16), pv[e]);
    }
    __syncthreads();              // all PV reads of Ab done; safe to alias

    // ---- cross-wave PV reduce via LDS (aliases Ab): pvred[w][h] ----
    float* pvred = reinterpret_cast<float*>(Ab);
    {
        float4 lo, hi;
        lo.x = pv[0]; lo.y = pv[1]; lo.z = pv[2]; lo.w = pv[3];
        hi.x = pv[4]; hi.y = pv[5]; hi.z = pv[6]; hi.w = pv[7];
        *reinterpret_cast<float4*>(pvred + wid * 512 + lane * 8)     = lo;
        *reinterpret_cast<float4*>(pvred + wid * 512 + lane * 8 + 4) = hi;
    }
    __syncthreads();
    {
        float s = 0.f;
#pragma unroll
        for (int w = 0; w < 8; ++w) s += pvred[w * 512 + tid];
        partial[((size_t)(b * 32 + chnk)) * H_N + tid] = s;
    }

#undef ALOAD
#undef AWRITE
#undef LOADB
#undef KSTEP
}

// ---------------------------------------------------------------------------
// K4: out[b][h] = (sum_c partial[b][c][h]) / (sum_c psum[b][c])
// ---------------------------------------------------------------------------
__global__ void k_out(const float* __restrict__ partial, const float* __restrict__ psum,
                      float* __restrict__ out) {
    int idx = blockIdx.x * 256 + threadIdx.x;   // 65536 outputs
    int b = idx >> 9, h = idx & 511;
    float s = 0.f, d = 0.f;
#pragma unroll
    for (int c = 0; c < 32; ++c) {
        s += partial[((size_t)(b * 32 + c)) * H_N + h];
        d += psum[b * 32 + c];
    }
    out[idx] = s / d;
}

extern "C" void kernel_launch(void* const* d_in, const int* in_sizes, int n_in,
                              void* d_out, int out_size, void* d_ws, size_t ws_size,
                              hipStream_t stream) {
    const float* query = (const float*)d_in[0];
    const float* key   = (const float*)d_in[1];
    const float* w1    = (const float*)d_in[2];
    const float* w2    = (const float*)d_in[3];
    const float* w_out = (const float*)d_in[4];
    float* out = (float*)d_out;

    char* ws = (char*)d_ws;
    unsigned short* w2p = (unsigned short*)(ws);             // 512 KB
    float* qh      = (float*)(ws + 524288);                  // 256 KB
    float* partial = (float*)(ws + 1048576);                 // 8 MB (128*32*512*4)
    float* psum    = (float*)(ws + 9437184);                 // 16 KB

    hipLaunchKernelGGL(k_w2prep, dim3(128),     dim3(256), 0, stream, w2, w2p);
    hipLaunchKernelGGL(k_qh,     dim3(128),     dim3(512), 0, stream, query, w1, qh);
    hipLaunchKernelGGL(k_scores, dim3(32, 128), dim3(512), 0, stream,
                       key, w2p, qh, w_out, partial, psum);
    hipLaunchKernelGGL(k_out,    dim3(256),     dim3(256), 0, stream, partial, psum, out);
}